// Round 6
// baseline (433.740 us; speedup 1.0000x reference)
//
#include <hip/hip_runtime.h>
#include <hip/hip_bf16.h>
#include <math.h>

#define B_ 128
#define SEQ_ 64
#define CH_ 256
#define PARTS_ 16
#define HID_ 64

typedef __attribute__((ext_vector_type(8))) short bf16x8;
typedef __attribute__((ext_vector_type(4))) float f32x4;

// ---- ws layout (bf16 elements), fragment-major: [p][kchunk][row][8] ----
// Wa1f/Wa2f: p, kc=96 (k1 = kc*8+e, k1 = tap*256 + c), j=64, e=8   : 786432 each
// Wb1f:      p, kc=8  (h  = kc*8+e),                   c=256, e=8  : 262144
// Wb2f:      p, kc=24 (k2 = kc*8+e, k2 = tap*64 + h),  c=256, e=8  : 786432
#define WA1_OFF 0
#define WA2_OFF (16 * 96 * 64 * 8)
#define WB1_OFF (2 * 16 * 96 * 64 * 8)
#define WB2_OFF (2 * 16 * 96 * 64 * 8 + 16 * 8 * 256 * 8)
#define WS_ELEMS (2 * 16 * 96 * 64 * 8 + 16 * 8 * 256 * 8 + 16 * 24 * 256 * 8)
#define WS_BYTES ((size_t)WS_ELEMS * 2)
#define XT_ELEMS ((size_t)B_ * PARTS_ * SEQ_ * CH_)
#define WS_FULL_BYTES (WS_BYTES + XT_ELEMS * 2)

#define NWTHREADS (16 * 96 * 64 * 8 + 16 * 8 * 256 * 8 + 16 * 24 * 256 * 8)  // 1835008
#define NWBLOCKS  (NWTHREADS / 256)                                          // 7168

__device__ __forceinline__ ushort f2bf(float f) {
    __hip_bfloat16 h = __float2bfloat16(f);
    return *reinterpret_cast<ushort*>(&h);
}
__device__ __forceinline__ float bf2f(ushort u) {
    __hip_bfloat16 h;
    *reinterpret_cast<ushort*>(&h) = u;
    return __bfloat162float(h);
}

// ========== fused pre-pass: x transpose (first xblocks) + weight reorder ==========
#define TS 264
__global__ __launch_bounds__(256) void prep_all(
    const float* __restrict__ x,
    const float* __restrict__ W1a, const float* __restrict__ W1b,
    const float* __restrict__ W2a, const float* __restrict__ W2b,
    ushort* __restrict__ ws, ushort* __restrict__ xT, int xblocks)
{
    __shared__ ushort tile[4][16 * TS];   // 33792 B
    const int bid = blockIdx.x;
    const int t = threadIdx.x;

    if (bid < xblocks) {
        // ---- x: 4 (b,s) rows per block; xT[b][p][s][c] = bf16(x[b][s][c][p]) ----
        const int base = bid * 4;
        #pragma unroll
        for (int r = 0; r < 4; ++r) {
            const float* src = x + (size_t)(base + r) * (CH_ * PARTS_);
            #pragma unroll
            for (int i = 0; i < 4; ++i) {
                int q = t + i * 256;                       // float4 index over [c][p]
                float4 v = reinterpret_cast<const float4*>(src)[q];
                int c = q >> 2, p0 = (q & 3) << 2;
                tile[r][(p0 + 0) * TS + c] = f2bf(v.x);
                tile[r][(p0 + 1) * TS + c] = f2bf(v.y);
                tile[r][(p0 + 2) * TS + c] = f2bf(v.z);
                tile[r][(p0 + 3) * TS + c] = f2bf(v.w);
            }
        }
        __syncthreads();
        const int p = t >> 4, cb = t & 15;
        #pragma unroll
        for (int r = 0; r < 4; ++r) {
            const int idx = base + r;
            const int b = idx >> 6, s = idx & 63;
            bf16x8 v0 = *reinterpret_cast<const bf16x8*>(&tile[r][p * TS + cb * 16]);
            bf16x8 v1 = *reinterpret_cast<const bf16x8*>(&tile[r][p * TS + cb * 16 + 8]);
            ushort* dst = xT + (((size_t)(b * 16 + p)) * 64 + s) * 256 + cb * 16;
            *reinterpret_cast<bf16x8*>(dst)     = v0;
            *reinterpret_cast<bf16x8*>(dst + 8) = v1;
        }
        return;
    }

    // ---- weights ----
    const int NA  = 16 * 96 * 64 * 8;
    const int NB1 = 16 * 8 * 256 * 8;
    const int NB2 = 16 * 24 * 256 * 8;
    int idx = (bid - xblocks) * 256 + t;
    if (idx < NA) {
        int e = idx & 7, j = (idx >> 3) & 63;
        int q = idx >> 9;                  // p*96 + kc
        int kc = q % 96, p = q / 96;
        int k1 = kc * 8 + e, tap = k1 >> 8, c = k1 & 255;
        size_t src = ((size_t)(p * 64 + j) * 256 + c) * 3 + tap;
        ws[WA1_OFF + idx] = f2bf(W1a[src]);
        ws[WA2_OFF + idx] = f2bf(W2a[src]);
    } else if (idx < NA + NB1) {
        int i2 = idx - NA;
        int e = i2 & 7, c = (i2 >> 3) & 255;
        int q = i2 >> 11;
        int kc = q & 7, p = q >> 3;
        int h = kc * 8 + e;
        ws[WB1_OFF + i2] = f2bf(W1b[((size_t)(p * 256 + c)) * 64 + h]);
    } else if (idx < NA + NB1 + NB2) {
        int i2 = idx - NA - NB1;
        int e = i2 & 7, c = (i2 >> 3) & 255;
        int q = i2 >> 11;
        int kc = q % 24, p = q / 24;
        int k2 = kc * 8 + e, tap = k2 >> 6, h = k2 & 63;
        ws[WB2_OFF + i2] = f2bf(W2b[(((size_t)(p * 256 + c)) * 64 + h) * 3 + tap]);
    }
}

// ========== main fused kernel ==========
#define XSTRIDE 264   // ushorts/row (16-B aligned rows)
#define XROWS   66    // row = s + 1; rows 0 and 65 are zero
#define HSTR    72    // ushorts/row for Ht1/Ht2

__global__ __launch_bounds__(256, 3) void tfa_mfma(
    const float* __restrict__ x,
    const ushort* __restrict__ ws,
    const ushort* __restrict__ xT,
    float* __restrict__ out)
{
    __shared__ __align__(16) ushort Xt[XROWS * XSTRIDE];   // 34848 B
    __shared__ __align__(16) ushort Ht1[64 * HSTR];        // 9216 B
    __shared__ __align__(16) ushort Ht2[66 * HSTR];        // 9504 B

    // XCD-aware mapping: XCD gets p in {2*xcd, 2*xcd+1}
    const int i = blockIdx.x;
    const int xcd = i & 7;
    const int k = i >> 3;
    const int p = (xcd << 1) | (k & 1);
    const int b = k >> 1;
    const int lblk = b * PARTS_ + p;

    const int t = threadIdx.x;
    const int lane = t & 63;
    const int wid = __builtin_amdgcn_readfirstlane(t >> 6);
    const int nlane = lane & 15;
    const int klane = lane >> 4;

    // ---- zero pad rows ----
    for (int q = t; q < XSTRIDE; q += 256) {
        Xt[q] = 0;
        Xt[65 * XSTRIDE + q] = 0;
    }
    for (int q = t; q < HSTR; q += 256) {
        Ht2[q] = 0;
        Ht2[65 * HSTR + q] = 0;
    }

    // ---- stage x slice into Xt[s+1][c] ----
    if (xT) {
        const ushort* xb = xT + ((size_t)lblk * SEQ_) * CH_;
        const int half = lane >> 5;
        const int col8 = (lane & 31) * 8;
        #pragma unroll
        for (int kk = 0; kk < 8; ++kk) {
            const int row = kk * 8 + wid * 2 + half;   // s
            bf16x8 v = *reinterpret_cast<const bf16x8*>(xb + (size_t)row * CH_ + col8);
            *reinterpret_cast<bf16x8*>(&Xt[(row + 1) * XSTRIDE + col8]) = v;
        }
    } else {
        const float* xb = x + (size_t)b * (SEQ_ * CH_ * PARTS_) + p;
        for (int cc = wid; cc < CH_; cc += 4) {
            float v = xb[((size_t)lane * CH_ + cc) * PARTS_];
            Xt[(lane + 1) * XSTRIDE + cc] = f2bf(v);
        }
    }
    __syncthreads();

    const ushort* wb1 = ws + WB1_OFF + ((size_t)p * 8 * 256 * 8);
    const ushort* wb2 = ws + WB2_OFF + ((size_t)p * 24 * 256 * 8);

    // ---- stage 1: wave owns j-tile (j = wid*16 + nlane); depth-4 weight prefetch ----
    {
        const ushort* wa1 = ws + WA1_OFF + ((size_t)p * 96 * 64 * 8);
        const ushort* wa2 = ws + WA2_OFF + ((size_t)p * 96 * 64 * 8);
        const int j = (wid << 4) + nlane;
        #define WA_ADDR(base, kkv) ((base) + (((size_t)((kkv) * 4 + klane) * 64 + j) << 3))

        f32x4 acc1[4], acc2[4];
        #pragma unroll
        for (int st = 0; st < 4; ++st) { acc1[st] = {0.f,0.f,0.f,0.f}; acc2[st] = {0.f,0.f,0.f,0.f}; }

        bf16x8 pa1[4], pa2[4];
        #pragma unroll
        for (int q = 0; q < 4; ++q) {
            pa1[q] = *reinterpret_cast<const bf16x8*>(WA_ADDR(wa1, q));
            pa2[q] = *reinterpret_cast<const bf16x8*>(WA_ADDR(wa2, q));
        }

        const int coff = klane << 3;
        #pragma unroll 1
        for (int kk0 = 0; kk0 < 24; kk0 += 4) {
            #pragma unroll
            for (int u = 0; u < 4; ++u) {
                const int kk = kk0 + u;
                const int kn = (kk + 4 < 24) ? (kk + 4) : 23;   // clamped prefetch
                bf16x8 n1 = *reinterpret_cast<const bf16x8*>(WA_ADDR(wa1, kn));
                bf16x8 n2 = *reinterpret_cast<const bf16x8*>(WA_ADDR(wa2, kn));
                const int tap = kk >> 3;
                const int c0 = ((kk & 7) << 5) + coff;
                const int rbase = nlane + tap;                  // row = s + tap
                #pragma unroll
                for (int st = 0; st < 4; ++st) {
                    bf16x8 bf = *reinterpret_cast<const bf16x8*>(&Xt[((st << 4) + rbase) * XSTRIDE + c0]);
                    acc1[st] = __builtin_amdgcn_mfma_f32_16x16x32_bf16(pa1[u], bf, acc1[st], 0, 0, 0);
                    acc2[st] = __builtin_amdgcn_mfma_f32_16x16x32_bf16(pa2[u], bf, acc2[st], 0, 0, 0);
                }
                pa1[u] = n1; pa2[u] = n2;
            }
        }
        #undef WA_ADDR

        // write Ht: D col = nlane -> s; row = klane*4 + r -> j
        #pragma unroll
        for (int st = 0; st < 4; ++st) {
            const int s = (st << 4) + nlane;
            const int jw = (wid << 4) + (klane << 2);
            #pragma unroll
            for (int r = 0; r < 4; ++r) {
                float v1 = acc1[st][r]; v1 = (v1 > 0.f) ? v1 : 0.01f * v1;
                Ht1[s * HSTR + jw + r] = f2bf(v1);
                float v2 = acc2[st][r]; v2 = (v2 > 0.f) ? v2 : 0.01f * v2;
                Ht2[(s + 1) * HSTR + jw + r] = f2bf(v2);
            }
        }
    }

    // ---- prefetch branch-1 stage-2 weight fragments BEFORE the barrier ----
    // (independent of Ht; identical for both halves)
    bf16x8 pb1[2][4];
    #pragma unroll
    for (int kk = 0; kk < 2; ++kk)
        #pragma unroll
        for (int ctl = 0; ctl < 4; ++ctl) {
            const int c = (wid << 6) + (ctl << 4) + nlane;
            pb1[kk][ctl] = *reinterpret_cast<const bf16x8*>(
                wb1 + ((((size_t)(kk * 4 + klane)) * 256 + c) << 3));
        }
    __syncthreads();

    // ---- stage 2 + epilogue: wave owns c-group (64 c), halves fully unrolled ----
    float pmax[4][4];
    #pragma unroll
    for (int ctl = 0; ctl < 4; ++ctl)
        #pragma unroll
        for (int r = 0; r < 4; ++r) pmax[ctl][r] = -INFINITY;

    const int koff = klane << 3;

    #pragma unroll
    for (int half = 0; half < 2; ++half) {
        const int st0 = half << 1;
        f32x4 l1[4][2], l2[4][2];
        #pragma unroll
        for (int ctl = 0; ctl < 4; ++ctl) {
            l1[ctl][0] = {0.f,0.f,0.f,0.f}; l1[ctl][1] = {0.f,0.f,0.f,0.f};
            l2[ctl][0] = {0.f,0.f,0.f,0.f}; l2[ctl][1] = {0.f,0.f,0.f,0.f};
        }

        // branch 1: conv1x1, K = 64 — weights from prefetched pb1
        #pragma unroll
        for (int kk = 0; kk < 2; ++kk) {
            bf16x8 bfr0 = *reinterpret_cast<const bf16x8*>(
                &Ht1[(((st0 + 0) << 4) + nlane) * HSTR + (kk << 5) + koff]);
            bf16x8 bfr1 = *reinterpret_cast<const bf16x8*>(
                &Ht1[(((st0 + 1) << 4) + nlane) * HSTR + (kk << 5) + koff]);
            #pragma unroll
            for (int ctl = 0; ctl < 4; ++ctl) {
                l1[ctl][0] = __builtin_amdgcn_mfma_f32_16x16x32_bf16(pb1[kk][ctl], bfr0, l1[ctl][0], 0, 0, 0);
                l1[ctl][1] = __builtin_amdgcn_mfma_f32_16x16x32_bf16(pb1[kk][ctl], bfr1, l1[ctl][1], 0, 0, 0);
            }
        }
        // branch 2: conv3, K = 192 (k2 = tap*64 + h)
        #pragma unroll
        for (int kk = 0; kk < 6; ++kk) {
            const int tap = kk >> 1;
            const int h0 = ((kk & 1) << 5) + koff;
            bf16x8 bfr0 = *reinterpret_cast<const bf16x8*>(
                &Ht2[(((st0 + 0) << 4) + nlane + tap) * HSTR + h0]);
            bf16x8 bfr1 = *reinterpret_cast<const bf16x8*>(
                &Ht2[(((st0 + 1) << 4) + nlane + tap) * HSTR + h0]);
            #pragma unroll
            for (int ctl = 0; ctl < 4; ++ctl) {
                const int c = (wid << 6) + (ctl << 4) + nlane;
                bf16x8 af = *reinterpret_cast<const bf16x8*>(
                    wb2 + ((((size_t)(kk * 4 + klane)) * 256 + c) << 3));
                l2[ctl][0] = __builtin_amdgcn_mfma_f32_16x16x32_bf16(af, bfr0, l2[ctl][0], 0, 0, 0);
                l2[ctl][1] = __builtin_amdgcn_mfma_f32_16x16x32_bf16(af, bfr1, l2[ctl][1], 0, 0, 0);
            }
        }

        // partial epilogue for this half's two s-tiles
        #pragma unroll
        for (int ctl = 0; ctl < 4; ++ctl) {
            #pragma unroll
            for (int r = 0; r < 4; ++r) {
                const int c = (wid << 6) + (ctl << 4) + (klane << 2) + r;
                #pragma unroll
                for (int sh = 0; sh < 2; ++sh) {
                    const int s = ((st0 + sh) << 4) + nlane;
                    const int rm2 = (s >= 1) ? (s - 1) : 0;
                    const int rp2 = (s <= 62) ? (s + 3) : 65;
                    const float xm2 = bf2f(Xt[rm2 * XSTRIDE + c]);
                    const float xm1 = bf2f(Xt[(s)     * XSTRIDE + c]);
                    const float x0  = bf2f(Xt[(s + 1) * XSTRIDE + c]);
                    const float xp1 = bf2f(Xt[(s + 2) * XSTRIDE + c]);
                    const float xp2 = bf2f(Xt[rp2 * XSTRIDE + c]);
                    const float avg3 = (xm1 + x0 + xp1) * (1.f / 3.f);
                    const float avg5 = (xm2 + xm1 + x0 + xp1 + xp2) * 0.2f;
                    float mx3 = x0;
                    if (s > 0)  mx3 = fmaxf(mx3, xm1);
                    if (s < 63) mx3 = fmaxf(mx3, xp1);
                    float mx5 = mx3;
                    if (s > 1)  mx5 = fmaxf(mx5, xm2);
                    if (s < 62) mx5 = fmaxf(mx5, xp2);
                    const float g1 = 1.f / (1.f + __expf(-l1[ctl][sh][r]));
                    const float g2 = 1.f / (1.f + __expf(-l2[ctl][sh][r]));
                    const float m = (avg3 + mx3) * g1 + (avg5 + mx5) * g2;
                    pmax[ctl][r] = fmaxf(pmax[ctl][r], m);
                }
            }
        }
    }

    // ---- final reduce over nlane (s) and write ----
    #pragma unroll
    for (int ctl = 0; ctl < 4; ++ctl) {
        #pragma unroll
        for (int r = 0; r < 4; ++r) {
            float m = pmax[ctl][r];
            m = fmaxf(m, __shfl_xor(m, 1, 64));
            m = fmaxf(m, __shfl_xor(m, 2, 64));
            m = fmaxf(m, __shfl_xor(m, 4, 64));
            m = fmaxf(m, __shfl_xor(m, 8, 64));
            if (nlane == 0) {
                const int c = (wid << 6) + (ctl << 4) + (klane << 2) + r;
                out[(size_t)lblk * CH_ + c] = m;
            }
        }
    }
}

// ========== fallback (fp32 kernel) if ws too small ==========
#define HPAD 68
__global__ __launch_bounds__(256, 1) void tfa_fused_fp32(
    const float* __restrict__ x,
    const float* __restrict__ W1a,
    const float* __restrict__ W1b,
    const float* __restrict__ W2a,
    const float* __restrict__ W2b,
    float* __restrict__ out)
{
    __shared__ float xs[CH_ * SEQ_];
    __shared__ float h1s[HID_ * HPAD];
    __shared__ float h2s[HID_ * HPAD];

    const int blk = blockIdx.x;
    const int b = blk >> 4;
    const int p = blk & 15;
    const int t = threadIdx.x;
    const int lane = t & 63;
    const int wid = __builtin_amdgcn_readfirstlane(t >> 6);

    {
        const float* xb = x + (size_t)b * (SEQ_ * CH_ * PARTS_) + p;
        const int s = lane;
        for (int cc = wid; cc < CH_; cc += 4)
            xs[cc * SEQ_ + s] = xb[((size_t)s * CH_ + cc) * PARTS_];
    }
    __syncthreads();

    const int jj = lane & 15;
    const int sg = lane >> 4;
    const int sbase = sg << 4;
    const float fl = (sg > 0) ? 1.f : 0.f;
    const float fr = (sg < 3) ? 1.f : 0.f;
    const int il  = (sg > 0) ? -1 : 0;
    const int ir  = (sg < 3) ? 16 : 0;
    const int ir2 = (sg < 3) ? 17 : 0;
    const int il2 = (sg > 0) ? -2 : 0;

    {
        const int j0 = wid * 16 + jj;
        float a1[16], a2[16];
        #pragma unroll
        for (int q = 0; q < 16; ++q) { a1[q] = 0.f; a2[q] = 0.f; }
        const float* w1p = W1a + (size_t)(p * HID_ + j0) * (CH_ * 3);
        const float* w2p = W2a + (size_t)(p * HID_ + j0) * (CH_ * 3);
        #pragma unroll 4
        for (int c = 0; c < CH_; ++c) {
            const float* xrow = &xs[c * SEQ_ + sbase];
            float xv[18];
            {
                float4 q;
                q = *(const float4*)(xrow);      xv[1]=q.x; xv[2]=q.y; xv[3]=q.z; xv[4]=q.w;
                q = *(const float4*)(xrow + 4);  xv[5]=q.x; xv[6]=q.y; xv[7]=q.z; xv[8]=q.w;
                q = *(const float4*)(xrow + 8);  xv[9]=q.x; xv[10]=q.y; xv[11]=q.z; xv[12]=q.w;
                q = *(const float4*)(xrow + 12); xv[13]=q.x; xv[14]=q.y; xv[15]=q.z; xv[16]=q.w;
            }
            xv[0]  = xrow[il] * fl;
            xv[17] = xrow[ir] * fr;
            const float w10 = w1p[c*3+0], w11 = w1p[c*3+1], w12 = w1p[c*3+2];
            const float w20 = w2p[c*3+0], w21 = w2p[c*3+1], w22 = w2p[c*3+2];
            #pragma unroll
            for (int q = 0; q < 16; ++q) {
                a1[q] = fmaf(xv[q], w10, fmaf(xv[q+1], w11, fmaf(xv[q+2], w12, a1[q])));
                a2[q] = fmaf(xv[q], w20, fmaf(xv[q+1], w21, fmaf(xv[q+2], w22, a2[q])));
            }
        }
        float* h1w = &h1s[j0 * HPAD + sbase];
        float* h2w = &h2s[j0 * HPAD + sbase];
        #pragma unroll
        for (int q4 = 0; q4 < 4; ++q4) {
            float4 v1, v2; float u;
            u = a1[4*q4+0]; v1.x = (u>0.f)?u:0.01f*u;
            u = a1[4*q4+1]; v1.y = (u>0.f)?u:0.01f*u;
            u = a1[4*q4+2]; v1.z = (u>0.f)?u:0.01f*u;
            u = a1[4*q4+3]; v1.w = (u>0.f)?u:0.01f*u;
            u = a2[4*q4+0]; v2.x = (u>0.f)?u:0.01f*u;
            u = a2[4*q4+1]; v2.y = (u>0.f)?u:0.01f*u;
            u = a2[4*q4+2]; v2.z = (u>0.f)?u:0.01f*u;
            u = a2[4*q4+3]; v2.w = (u>0.f)?u:0.01f*u;
            *(float4*)(h1w + 4*q4) = v1;
            *(float4*)(h2w + 4*q4) = v2;
        }
    }
    __syncthreads();

    {
        const int cbase = wid * 64;
        float l1[4][16], l2[4][16];
        #pragma unroll
        for (int ch = 0; ch < 4; ++ch)
            #pragma unroll
            for (int q = 0; q < 16; ++q) { l1[ch][q] = 0.f; l2[ch][q] = 0.f; }
        #pragma unroll 2
        for (int h = 0; h < HID_; ++h) {
            const float* h1row = &h1s[h * HPAD + sbase];
            const float* h2row = &h2s[h * HPAD + sbase];
            float hv1[16], hv2[18];
            {
                float4 q;
                q = *(const float4*)(h1row);      hv1[0]=q.x; hv1[1]=q.y; hv1[2]=q.z; hv1[3]=q.w;
                q = *(const float4*)(h1row + 4);  hv1[4]=q.x; hv1[5]=q.y; hv1[6]=q.z; hv1[7]=q.w;
                q = *(const float4*)(h1row + 8);  hv1[8]=q.x; hv1[9]=q.y; hv1[10]=q.z; hv1[11]=q.w;
                q = *(const float4*)(h1row + 12); hv1[12]=q.x; hv1[13]=q.y; hv1[14]=q.z; hv1[15]=q.w;
                q = *(const float4*)(h2row);      hv2[1]=q.x; hv2[2]=q.y; hv2[3]=q.z; hv2[4]=q.w;
                q = *(const float4*)(h2row + 4);  hv2[5]=q.x; hv2[6]=q.y; hv2[7]=q.z; hv2[8]=q.w;
                q = *(const float4*)(h2row + 8);  hv2[9]=q.x; hv2[10]=q.y; hv2[11]=q.z; hv2[12]=q.w;
                q = *(const float4*)(h2row + 12); hv2[13]=q.x; hv2[14]=q.y; hv2[15]=q.z; hv2[16]=q.w;
            }
            hv2[0]  = h2row[il] * fl;
            hv2[17] = h2row[ir] * fr;
            #pragma unroll
            for (int ch = 0; ch < 4; ++ch) {
                const int c = cbase + ch * 16 + jj;
                const float wb1 = W1b[((size_t)p * CH_ + c) * HID_ + h];
                const float* w2q = W2b + ((size_t)(p * CH_ + c) * HID_ + h) * 3;
                const float wa = w2q[0], wb = w2q[1], wc = w2q[2];
                #pragma unroll
                for (int q = 0; q < 16; ++q) {
                    l1[ch][q] = fmaf(hv1[q], wb1, l1[ch][q]);
                    l2[ch][q] = fmaf(hv2[q], wa, fmaf(hv2[q+1], wb, fmaf(hv2[q+2], wc, l2[ch][q])));
                }
            }
        }
        #pragma unroll
        for (int ch = 0; ch < 4; ++ch) {
            const int c = cbase + ch * 16 + jj;
            const float* xrow = &xs[c * SEQ_ + sbase];
            float xp[20];
            {
                float4 q;
                q = *(const float4*)(xrow);      xp[2]=q.x; xp[3]=q.y; xp[4]=q.z; xp[5]=q.w;
                q = *(const float4*)(xrow + 4);  xp[6]=q.x; xp[7]=q.y; xp[8]=q.z; xp[9]=q.w;
                q = *(const float4*)(xrow + 8);  xp[10]=q.x; xp[11]=q.y; xp[12]=q.z; xp[13]=q.w;
                q = *(const float4*)(xrow + 12); xp[14]=q.x; xp[15]=q.y; xp[16]=q.z; xp[17]=q.w;
            }
            xp[0]  = xrow[il2] * fl;
            xp[1]  = xrow[il]  * fl;
            xp[18] = xrow[ir]  * fr;
            xp[19] = xrow[ir2] * fr;
            float mloc = -INFINITY;
            #pragma unroll
            for (int q = 0; q < 16; ++q) {
                const int s = sbase + q;
                const float x0  = xp[q+2];
                const float am1 = xp[q+1], ap1 = xp[q+3];
                const float am2 = xp[q],   ap2 = xp[q+4];
                const float avg3 = (am1 + x0 + ap1) * (1.f / 3.f);
                const float avg5 = (am2 + am1 + x0 + ap1 + ap2) * 0.2f;
                float mx3 = x0;
                if (s > 0)  mx3 = fmaxf(mx3, am1);
                if (s < 63) mx3 = fmaxf(mx3, ap1);
                float mx5 = mx3;
                if (s > 1)  mx5 = fmaxf(mx5, am2);
                if (s < 62) mx5 = fmaxf(mx5, ap2);
                const float g1 = 1.f / (1.f + __expf(-l1[ch][q]));
                const float g2 = 1.f / (1.f + __expf(-l2[ch][q]));
                const float m = (avg3 + mx3) * g1 + (avg5 + mx5) * g2;
                mloc = fmaxf(mloc, m);
            }
            mloc = fmaxf(mloc, __shfl_xor(mloc, 16, 64));
            mloc = fmaxf(mloc, __shfl_xor(mloc, 32, 64));
            if (sg == 0)
                out[(size_t)blk * CH_ + c] = mloc;
        }
    }
}

extern "C" void kernel_launch(void* const* d_in, const int* in_sizes, int n_in,
                              void* d_out, int out_size, void* d_ws, size_t ws_size,
                              hipStream_t stream) {
    const float* x   = (const float*)d_in[0];
    const float* W1a = (const float*)d_in[1];
    const float* W1b = (const float*)d_in[2];
    const float* W2a = (const float*)d_in[3];
    const float* W2b = (const float*)d_in[4];
    float* out = (float*)d_out;

    if (ws_size >= WS_BYTES) {
        ushort* ws = (ushort*)d_ws;
        ushort* xT = nullptr;
        int xblocks = 0;
        if (ws_size >= WS_FULL_BYTES) {
            xT = ws + WS_ELEMS;
            xblocks = 2048;   // 8192 (b,s) rows / 4 per block
        }
        prep_all<<<dim3(xblocks + NWBLOCKS), dim3(256), 0, stream>>>(
            x, W1a, W1b, W2a, W2b, ws, xT, xblocks);
        tfa_mfma<<<dim3(B_ * PARTS_), dim3(256), 0, stream>>>(x, ws, xT, out);
    } else {
        tfa_fused_fp32<<<dim3(B_ * PARTS_), dim3(256), 0, stream>>>(x, W1a, W1b, W2a, W2b, out);
    }
}

// Round 7
// 353.852 us; speedup vs baseline: 1.2258x; 1.2258x over previous
//
#include <hip/hip_runtime.h>
#include <hip/hip_bf16.h>
#include <math.h>

#define B_ 128
#define SEQ_ 64
#define CH_ 256
#define PARTS_ 16
#define HID_ 64

typedef __attribute__((ext_vector_type(8))) short bf16x8;
typedef __attribute__((ext_vector_type(4))) float f32x4;

// ---- ws layout (bf16 elements), fragment-major: [p][kchunk][row][8] ----
// Wa1f/Wa2f: p, kc=96 (k1 = kc*8+e, k1 = tap*256 + c), j=64, e=8   : 786432 each
// Wb1f:      p, kc=8  (h  = kc*8+e),                   c=256, e=8  : 262144
// Wb2f:      p, kc=24 (k2 = kc*8+e, k2 = tap*64 + h),  c=256, e=8  : 786432
#define WA1_OFF 0
#define WA2_OFF (16 * 96 * 64 * 8)
#define WB1_OFF (2 * 16 * 96 * 64 * 8)
#define WB2_OFF (2 * 16 * 96 * 64 * 8 + 16 * 8 * 256 * 8)
#define WS_ELEMS (2 * 16 * 96 * 64 * 8 + 16 * 8 * 256 * 8 + 16 * 24 * 256 * 8)
#define WS_BYTES ((size_t)WS_ELEMS * 2)
#define XT_ELEMS ((size_t)B_ * PARTS_ * SEQ_ * CH_)
#define WS_FULL_BYTES (WS_BYTES + XT_ELEMS * 2)

#define NWTHREADS (16 * 96 * 64 * 8 + 16 * 8 * 256 * 8 + 16 * 24 * 256 * 8)  // 1835008
#define NWBLOCKS  (NWTHREADS / 256)                                          // 7168
#define XBLOCKS   (B_ * SEQ_)                                                // 8192

__device__ __forceinline__ ushort f2bf(float f) {
    __hip_bfloat16 h = __float2bfloat16(f);
    return *reinterpret_cast<ushort*>(&h);
}
__device__ __forceinline__ float bf2f(ushort u) {
    __hip_bfloat16 h;
    *reinterpret_cast<ushort*>(&h) = u;
    return __bfloat162float(h);
}

// ========== fused pre-pass: x transpose (blocks < XBLOCKS) + weight reorder ==========
// x part: one (b,s) row per block. f32 LDS tile [16 p][260] (stride 260 -> 2-way
// bank aliasing on ds_write_b32 = free; 16.6 KB -> no occupancy penalty for the
// weight blocks sharing this kernel).
#define PXSTR 260
__global__ __launch_bounds__(256) void prep_all(
    const float* __restrict__ x,
    const float* __restrict__ W1a, const float* __restrict__ W1b,
    const float* __restrict__ W2a, const float* __restrict__ W2b,
    ushort* __restrict__ ws, ushort* __restrict__ xT, int xblocks)
{
    __shared__ float tile[16 * PXSTR];   // 16640 B
    const int bid = blockIdx.x;
    const int t = threadIdx.x;

    if (bid < xblocks) {
        const int b = bid >> 6, s = bid & 63;
        const float* src = x + (size_t)(b * 64 + s) * (CH_ * PARTS_);
        #pragma unroll
        for (int i = 0; i < 4; ++i) {
            int q = t + i * 256;                  // float4 index over [c][p]
            float4 v = reinterpret_cast<const float4*>(src)[q];
            int c = q >> 2, p0 = (q & 3) << 2;
            tile[(p0 + 0) * PXSTR + c] = v.x;
            tile[(p0 + 1) * PXSTR + c] = v.y;
            tile[(p0 + 2) * PXSTR + c] = v.z;
            tile[(p0 + 3) * PXSTR + c] = v.w;
        }
        __syncthreads();
        const int p = t >> 4, cb = t & 15;
        const float* row = &tile[p * PXSTR + cb * 16];
        bf16x8 v0, v1;
        #pragma unroll
        for (int k = 0; k < 8; ++k) v0[k] = (short)f2bf(row[k]);
        #pragma unroll
        for (int k = 0; k < 8; ++k) v1[k] = (short)f2bf(row[8 + k]);
        ushort* dst = xT + (((size_t)(b * 16 + p)) * 64 + s) * 256 + cb * 16;
        *reinterpret_cast<bf16x8*>(dst)     = v0;
        *reinterpret_cast<bf16x8*>(dst + 8) = v1;
        return;
    }

    // ---- weights ----
    const int NA  = 16 * 96 * 64 * 8;
    const int NB1 = 16 * 8 * 256 * 8;
    const int NB2 = 16 * 24 * 256 * 8;
    int idx = (bid - xblocks) * 256 + t;
    if (idx < NA) {
        int e = idx & 7, j = (idx >> 3) & 63;
        int q = idx >> 9;                  // p*96 + kc
        int kc = q % 96, p = q / 96;
        int k1 = kc * 8 + e, tap = k1 >> 8, c = k1 & 255;
        size_t src = ((size_t)(p * 64 + j) * 256 + c) * 3 + tap;
        ws[WA1_OFF + idx] = f2bf(W1a[src]);
        ws[WA2_OFF + idx] = f2bf(W2a[src]);
    } else if (idx < NA + NB1) {
        int i2 = idx - NA;
        int e = i2 & 7, c = (i2 >> 3) & 255;
        int q = i2 >> 11;
        int kc = q & 7, p = q >> 3;
        int h = kc * 8 + e;
        ws[WB1_OFF + i2] = f2bf(W1b[((size_t)(p * 256 + c)) * 64 + h]);
    } else if (idx < NA + NB1 + NB2) {
        int i2 = idx - NA - NB1;
        int e = i2 & 7, c = (i2 >> 3) & 255;
        int q = i2 >> 11;
        int kc = q % 24, p = q / 24;
        int k2 = kc * 8 + e, tap = k2 >> 6, h = k2 & 63;
        ws[WB2_OFF + i2] = f2bf(W2b[(((size_t)(p * 256 + c)) * 64 + h) * 3 + tap]);
    }
}

// ========== main fused kernel (round-5 structure, measured 171 us) ==========
#define XSTRIDE 264   // ushorts/row (16-B aligned rows)
#define XROWS   66    // row = s + 1; rows 0 and 65 are zero
#define HSTR    72    // ushorts/row for Ht1/Ht2

__global__ __launch_bounds__(256, 3) void tfa_mfma(
    const float* __restrict__ x,
    const ushort* __restrict__ ws,
    const ushort* __restrict__ xT,
    float* __restrict__ out)
{
    __shared__ __align__(16) ushort Xt[XROWS * XSTRIDE];   // 34848 B
    __shared__ __align__(16) ushort Ht1[64 * HSTR];        // 9216 B  row = s
    __shared__ __align__(16) ushort Ht2[66 * HSTR];        // 9504 B  row = s+tap (s'+1)

    // XCD-aware mapping: XCD gets p in {2*xcd, 2*xcd+1} -> L2-resident weights
    const int i = blockIdx.x;
    const int xcd = i & 7;
    const int k = i >> 3;
    const int p = (xcd << 1) | (k & 1);
    const int b = k >> 1;
    const int lblk = b * PARTS_ + p;

    const int t = threadIdx.x;
    const int lane = t & 63;
    const int wid = __builtin_amdgcn_readfirstlane(t >> 6);
    const int nlane = lane & 15;
    const int klane = lane >> 4;

    // ---- zero pad rows ----
    for (int q = t; q < XSTRIDE; q += 256) {
        Xt[q] = 0;
        Xt[65 * XSTRIDE + q] = 0;
    }
    for (int q = t; q < HSTR; q += 256) {
        Ht2[q] = 0;
        Ht2[65 * HSTR + q] = 0;
    }

    // ---- stage x slice into Xt[s+1][c] ----
    if (xT) {
        const ushort* xb = xT + ((size_t)lblk * SEQ_) * CH_;
        const int half = lane >> 5;
        const int col8 = (lane & 31) * 8;
        #pragma unroll
        for (int kk = 0; kk < 8; ++kk) {
            const int row = kk * 8 + wid * 2 + half;   // s
            bf16x8 v = *reinterpret_cast<const bf16x8*>(xb + (size_t)row * CH_ + col8);
            *reinterpret_cast<bf16x8*>(&Xt[(row + 1) * XSTRIDE + col8]) = v;
        }
    } else {
        const float* xb = x + (size_t)b * (SEQ_ * CH_ * PARTS_) + p;
        for (int cc = wid; cc < CH_; cc += 4) {
            float v = xb[((size_t)lane * CH_ + cc) * PARTS_];
            Xt[(lane + 1) * XSTRIDE + cc] = f2bf(v);
        }
    }
    __syncthreads();

    // ---- stage 1: wave owns j-tile (j = wid*16 + nlane); depth-2 weight prefetch ----
    {
        const ushort* wa1 = ws + WA1_OFF + ((size_t)p * 96 * 64 * 8);
        const ushort* wa2 = ws + WA2_OFF + ((size_t)p * 96 * 64 * 8);
        const int j = (wid << 4) + nlane;
        #define WA_ADDR(base, kkv) ((base) + (((size_t)((kkv) * 4 + klane) * 64 + j) << 3))

        f32x4 acc1[4], acc2[4];
        #pragma unroll
        for (int st = 0; st < 4; ++st) { acc1[st] = {0.f,0.f,0.f,0.f}; acc2[st] = {0.f,0.f,0.f,0.f}; }

        bf16x8 pa1[2], pa2[2];
        pa1[0] = *reinterpret_cast<const bf16x8*>(WA_ADDR(wa1, 0));
        pa2[0] = *reinterpret_cast<const bf16x8*>(WA_ADDR(wa2, 0));
        pa1[1] = *reinterpret_cast<const bf16x8*>(WA_ADDR(wa1, 1));
        pa2[1] = *reinterpret_cast<const bf16x8*>(WA_ADDR(wa2, 1));

        const int coff = klane << 3;
        #pragma unroll 1
        for (int kk = 0; kk < 24; kk += 2) {
            {   // even sub-iter: uses pa[0], prefetch kk+2
                const int kn = (kk + 2 < 24) ? (kk + 2) : 22;
                bf16x8 n1 = *reinterpret_cast<const bf16x8*>(WA_ADDR(wa1, kn));
                bf16x8 n2 = *reinterpret_cast<const bf16x8*>(WA_ADDR(wa2, kn));
                const int tap = kk >> 3;
                const int c0 = ((kk & 7) << 5) + coff;
                const int rbase = nlane + tap;          // row = s + tap
                #pragma unroll
                for (int st = 0; st < 4; ++st) {
                    bf16x8 bf = *reinterpret_cast<const bf16x8*>(&Xt[((st << 4) + rbase) * XSTRIDE + c0]);
                    acc1[st] = __builtin_amdgcn_mfma_f32_16x16x32_bf16(pa1[0], bf, acc1[st], 0, 0, 0);
                    acc2[st] = __builtin_amdgcn_mfma_f32_16x16x32_bf16(pa2[0], bf, acc2[st], 0, 0, 0);
                }
                pa1[0] = n1; pa2[0] = n2;
            }
            {   // odd sub-iter: uses pa[1], prefetch kk+3
                const int k1 = kk + 1;
                const int kn = (k1 + 2 < 24) ? (k1 + 2) : 23;
                bf16x8 n1 = *reinterpret_cast<const bf16x8*>(WA_ADDR(wa1, kn));
                bf16x8 n2 = *reinterpret_cast<const bf16x8*>(WA_ADDR(wa2, kn));
                const int tap = k1 >> 3;
                const int c0 = ((k1 & 7) << 5) + coff;
                const int rbase = nlane + tap;
                #pragma unroll
                for (int st = 0; st < 4; ++st) {
                    bf16x8 bf = *reinterpret_cast<const bf16x8*>(&Xt[((st << 4) + rbase) * XSTRIDE + c0]);
                    acc1[st] = __builtin_amdgcn_mfma_f32_16x16x32_bf16(pa1[1], bf, acc1[st], 0, 0, 0);
                    acc2[st] = __builtin_amdgcn_mfma_f32_16x16x32_bf16(pa2[1], bf, acc2[st], 0, 0, 0);
                }
                pa1[1] = n1; pa2[1] = n2;
            }
        }
        #undef WA_ADDR

        // write Ht: D col = nlane -> s within tile; row = klane*4 + r -> j within tile
        #pragma unroll
        for (int st = 0; st < 4; ++st) {
            const int s = (st << 4) + nlane;
            const int jw = (wid << 4) + (klane << 2);
            #pragma unroll
            for (int r = 0; r < 4; ++r) {
                float v1 = acc1[st][r]; v1 = (v1 > 0.f) ? v1 : 0.01f * v1;
                Ht1[s * HSTR + jw + r] = f2bf(v1);
                float v2 = acc2[st][r]; v2 = (v2 > 0.f) ? v2 : 0.01f * v2;
                Ht2[(s + 1) * HSTR + jw + r] = f2bf(v2);
            }
        }
    }
    __syncthreads();

    // ---- stage 2 + epilogue: wave owns c-group (64 c), two st-pass halves ----
    const ushort* wb1 = ws + WB1_OFF + ((size_t)p * 8 * 256 * 8);
    const ushort* wb2 = ws + WB2_OFF + ((size_t)p * 24 * 256 * 8);

    float pmax[4][4];
    #pragma unroll
    for (int ctl = 0; ctl < 4; ++ctl)
        #pragma unroll
        for (int r = 0; r < 4; ++r) pmax[ctl][r] = -INFINITY;

    const int koff = klane << 3;

    #pragma unroll 1
    for (int half = 0; half < 2; ++half) {
        const int st0 = half << 1;
        f32x4 l1[4][2], l2[4][2];
        #pragma unroll
        for (int ctl = 0; ctl < 4; ++ctl) {
            l1[ctl][0] = {0.f,0.f,0.f,0.f}; l1[ctl][1] = {0.f,0.f,0.f,0.f};
            l2[ctl][0] = {0.f,0.f,0.f,0.f}; l2[ctl][1] = {0.f,0.f,0.f,0.f};
        }

        // branch 1: conv1x1, K = 64 (kc = kk*4 + klane)
        #pragma unroll
        for (int kk = 0; kk < 2; ++kk) {
            bf16x8 bfr0 = *reinterpret_cast<const bf16x8*>(
                &Ht1[(((st0 + 0) << 4) + nlane) * HSTR + (kk << 5) + koff]);
            bf16x8 bfr1 = *reinterpret_cast<const bf16x8*>(
                &Ht1[(((st0 + 1) << 4) + nlane) * HSTR + (kk << 5) + koff]);
            #pragma unroll
            for (int ctl = 0; ctl < 4; ++ctl) {
                const int c = (wid << 6) + (ctl << 4) + nlane;
                bf16x8 af = *reinterpret_cast<const bf16x8*>(
                    wb1 + ((((size_t)(kk * 4 + klane)) * 256 + c) << 3));
                l1[ctl][0] = __builtin_amdgcn_mfma_f32_16x16x32_bf16(af, bfr0, l1[ctl][0], 0, 0, 0);
                l1[ctl][1] = __builtin_amdgcn_mfma_f32_16x16x32_bf16(af, bfr1, l1[ctl][1], 0, 0, 0);
            }
        }
        // branch 2: conv3, K = 192 (k2 = tap*64 + h)
        #pragma unroll
        for (int kk = 0; kk < 6; ++kk) {
            const int tap = kk >> 1;
            const int h0 = ((kk & 1) << 5) + koff;
            bf16x8 bfr0 = *reinterpret_cast<const bf16x8*>(
                &Ht2[(((st0 + 0) << 4) + nlane + tap) * HSTR + h0]);
            bf16x8 bfr1 = *reinterpret_cast<const bf16x8*>(
                &Ht2[(((st0 + 1) << 4) + nlane + tap) * HSTR + h0]);
            #pragma unroll
            for (int ctl = 0; ctl < 4; ++ctl) {
                const int c = (wid << 6) + (ctl << 4) + nlane;
                bf16x8 af = *reinterpret_cast<const bf16x8*>(
                    wb2 + ((((size_t)(kk * 4 + klane)) * 256 + c) << 3));
                l2[ctl][0] = __builtin_amdgcn_mfma_f32_16x16x32_bf16(af, bfr0, l2[ctl][0], 0, 0, 0);
                l2[ctl][1] = __builtin_amdgcn_mfma_f32_16x16x32_bf16(af, bfr1, l2[ctl][1], 0, 0, 0);
            }
        }

        // partial epilogue for this half's two s-tiles
        #pragma unroll
        for (int ctl = 0; ctl < 4; ++ctl) {
            #pragma unroll
            for (int r = 0; r < 4; ++r) {
                const int c = (wid << 6) + (ctl << 4) + (klane << 2) + r;
                #pragma unroll
                for (int sh = 0; sh < 2; ++sh) {
                    const int s = ((st0 + sh) << 4) + nlane;
                    const int rm2 = (s >= 1) ? (s - 1) : 0;
                    const int rp2 = (s <= 62) ? (s + 3) : 65;
                    const float xm2 = bf2f(Xt[rm2 * XSTRIDE + c]);
                    const float xm1 = bf2f(Xt[(s)     * XSTRIDE + c]);
                    const float x0  = bf2f(Xt[(s + 1) * XSTRIDE + c]);
                    const float xp1 = bf2f(Xt[(s + 2) * XSTRIDE + c]);
                    const float xp2 = bf2f(Xt[rp2 * XSTRIDE + c]);
                    const float avg3 = (xm1 + x0 + xp1) * (1.f / 3.f);
                    const float avg5 = (xm2 + xm1 + x0 + xp1 + xp2) * 0.2f;
                    float mx3 = x0;
                    if (s > 0)  mx3 = fmaxf(mx3, xm1);
                    if (s < 63) mx3 = fmaxf(mx3, xp1);
                    float mx5 = mx3;
                    if (s > 1)  mx5 = fmaxf(mx5, xm2);
                    if (s < 62) mx5 = fmaxf(mx5, xp2);
                    const float g1 = 1.f / (1.f + __expf(-l1[ctl][sh][r]));
                    const float g2 = 1.f / (1.f + __expf(-l2[ctl][sh][r]));
                    const float m = (avg3 + mx3) * g1 + (avg5 + mx5) * g2;
                    pmax[ctl][r] = fmaxf(pmax[ctl][r], m);
                }
            }
        }
    }

    // ---- final reduce over nlane (s) and write ----
    #pragma unroll
    for (int ctl = 0; ctl < 4; ++ctl) {
        #pragma unroll
        for (int r = 0; r < 4; ++r) {
            float m = pmax[ctl][r];
            m = fmaxf(m, __shfl_xor(m, 1, 64));
            m = fmaxf(m, __shfl_xor(m, 2, 64));
            m = fmaxf(m, __shfl_xor(m, 4, 64));
            m = fmaxf(m, __shfl_xor(m, 8, 64));
            if (nlane == 0) {
                const int c = (wid << 6) + (ctl << 4) + (klane << 2) + r;
                out[(size_t)lblk * CH_ + c] = m;
            }
        }
    }
}

// ========== fallback (fp32 kernel) if ws too small ==========
#define HPAD 68
__global__ __launch_bounds__(256, 1) void tfa_fused_fp32(
    const float* __restrict__ x,
    const float* __restrict__ W1a,
    const float* __restrict__ W1b,
    const float* __restrict__ W2a,
    const float* __restrict__ W2b,
    float* __restrict__ out)
{
    __shared__ float xs[CH_ * SEQ_];
    __shared__ float h1s[HID_ * HPAD];
    __shared__ float h2s[HID_ * HPAD];

    const int blk = blockIdx.x;
    const int b = blk >> 4;
    const int p = blk & 15;
    const int t = threadIdx.x;
    const int lane = t & 63;
    const int wid = __builtin_amdgcn_readfirstlane(t >> 6);

    {
        const float* xb = x + (size_t)b * (SEQ_ * CH_ * PARTS_) + p;
        const int s = lane;
        for (int cc = wid; cc < CH_; cc += 4)
            xs[cc * SEQ_ + s] = xb[((size_t)s * CH_ + cc) * PARTS_];
    }
    __syncthreads();

    const int jj = lane & 15;
    const int sg = lane >> 4;
    const int sbase = sg << 4;
    const float fl = (sg > 0) ? 1.f : 0.f;
    const float fr = (sg < 3) ? 1.f : 0.f;
    const int il  = (sg > 0) ? -1 : 0;
    const int ir  = (sg < 3) ? 16 : 0;
    const int ir2 = (sg < 3) ? 17 : 0;
    const int il2 = (sg > 0) ? -2 : 0;

    {
        const int j0 = wid * 16 + jj;
        float a1[16], a2[16];
        #pragma unroll
        for (int q = 0; q < 16; ++q) { a1[q] = 0.f; a2[q] = 0.f; }
        const float* w1p = W1a + (size_t)(p * HID_ + j0) * (CH_ * 3);
        const float* w2p = W2a + (size_t)(p * HID_ + j0) * (CH_ * 3);
        #pragma unroll 4
        for (int c = 0; c < CH_; ++c) {
            const float* xrow = &xs[c * SEQ_ + sbase];
            float xv[18];
            {
                float4 q;
                q = *(const float4*)(xrow);      xv[1]=q.x; xv[2]=q.y; xv[3]=q.z; xv[4]=q.w;
                q = *(const float4*)(xrow + 4);  xv[5]=q.x; xv[6]=q.y; xv[7]=q.z; xv[8]=q.w;
                q = *(const float4*)(xrow + 8);  xv[9]=q.x; xv[10]=q.y; xv[11]=q.z; xv[12]=q.w;
                q = *(const float4*)(xrow + 12); xv[13]=q.x; xv[14]=q.y; xv[15]=q.z; xv[16]=q.w;
            }
            xv[0]  = xrow[il] * fl;
            xv[17] = xrow[ir] * fr;
            const float w10 = w1p[c*3+0], w11 = w1p[c*3+1], w12 = w1p[c*3+2];
            const float w20 = w2p[c*3+0], w21 = w2p[c*3+1], w22 = w2p[c*3+2];
            #pragma unroll
            for (int q = 0; q < 16; ++q) {
                a1[q] = fmaf(xv[q], w10, fmaf(xv[q+1], w11, fmaf(xv[q+2], w12, a1[q])));
                a2[q] = fmaf(xv[q], w20, fmaf(xv[q+1], w21, fmaf(xv[q+2], w22, a2[q])));
            }
        }
        float* h1w = &h1s[j0 * HPAD + sbase];
        float* h2w = &h2s[j0 * HPAD + sbase];
        #pragma unroll
        for (int q4 = 0; q4 < 4; ++q4) {
            float4 v1, v2; float u;
            u = a1[4*q4+0]; v1.x = (u>0.f)?u:0.01f*u;
            u = a1[4*q4+1]; v1.y = (u>0.f)?u:0.01f*u;
            u = a1[4*q4+2]; v1.z = (u>0.f)?u:0.01f*u;
            u = a1[4*q4+3]; v1.w = (u>0.f)?u:0.01f*u;
            u = a2[4*q4+0]; v2.x = (u>0.f)?u:0.01f*u;
            u = a2[4*q4+1]; v2.y = (u>0.f)?u:0.01f*u;
            u = a2[4*q4+2]; v2.z = (u>0.f)?u:0.01f*u;
            u = a2[4*q4+3]; v2.w = (u>0.f)?u:0.01f*u;
            *(float4*)(h1w + 4*q4) = v1;
            *(float4*)(h2w + 4*q4) = v2;
        }
    }
    __syncthreads();

    {
        const int cbase = wid * 64;
        float l1[4][16], l2[4][16];
        #pragma unroll
        for (int ch = 0; ch < 4; ++ch)
            #pragma unroll
            for (int q = 0; q < 16; ++q) { l1[ch][q] = 0.f; l2[ch][q] = 0.f; }
        #pragma unroll 2
        for (int h = 0; h < HID_; ++h) {
            const float* h1row = &h1s[h * HPAD + sbase];
            const float* h2row = &h2s[h * HPAD + sbase];
            float hv1[16], hv2[18];
            {
                float4 q;
                q = *(const float4*)(h1row);      hv1[0]=q.x; hv1[1]=q.y; hv1[2]=q.z; hv1[3]=q.w;
                q = *(const float4*)(h1row + 4);  hv1[4]=q.x; hv1[5]=q.y; hv1[6]=q.z; hv1[7]=q.w;
                q = *(const float4*)(h1row + 8);  hv1[8]=q.x; hv1[9]=q.y; hv1[10]=q.z; hv1[11]=q.w;
                q = *(const float4*)(h1row + 12); hv1[12]=q.x; hv1[13]=q.y; hv1[14]=q.z; hv1[15]=q.w;
                q = *(const float4*)(h2row);      hv2[1]=q.x; hv2[2]=q.y; hv2[3]=q.z; hv2[4]=q.w;
                q = *(const float4*)(h2row + 4);  hv2[5]=q.x; hv2[6]=q.y; hv2[7]=q.z; hv2[8]=q.w;
                q = *(const float4*)(h2row + 8);  hv2[9]=q.x; hv2[10]=q.y; hv2[11]=q.z; hv2[12]=q.w;
                q = *(const float4*)(h2row + 12); hv2[13]=q.x; hv2[14]=q.y; hv2[15]=q.z; hv2[16]=q.w;
            }
            hv2[0]  = h2row[il] * fl;
            hv2[17] = h2row[ir] * fr;
            #pragma unroll
            for (int ch = 0; ch < 4; ++ch) {
                const int c = cbase + ch * 16 + jj;
                const float wb1 = W1b[((size_t)p * CH_ + c) * HID_ + h];
                const float* w2q = W2b + ((size_t)(p * CH_ + c) * HID_ + h) * 3;
                const float wa = w2q[0], wb = w2q[1], wc = w2q[2];
                #pragma unroll
                for (int q = 0; q < 16; ++q) {
                    l1[ch][q] = fmaf(hv1[q], wb1, l1[ch][q]);
                    l2[ch][q] = fmaf(hv2[q], wa, fmaf(hv2[q+1], wb, fmaf(hv2[q+2], wc, l2[ch][q])));
                }
            }
        }
        #pragma unroll
        for (int ch = 0; ch < 4; ++ch) {
            const int c = cbase + ch * 16 + jj;
            const float* xrow = &xs[c * SEQ_ + sbase];
            float xp[20];
            {
                float4 q;
                q = *(const float4*)(xrow);      xp[2]=q.x; xp[3]=q.y; xp[4]=q.z; xp[5]=q.w;
                q = *(const float4*)(xrow + 4);  xp[6]=q.x; xp[7]=q.y; xp[8]=q.z; xp[9]=q.w;
                q = *(const float4*)(xrow + 8);  xp[10]=q.x; xp[11]=q.y; xp[12]=q.z; xp[13]=q.w;
                q = *(const float4*)(xrow + 12); xp[14]=q.x; xp[15]=q.y; xp[16]=q.z; xp[17]=q.w;
            }
            xp[0]  = xrow[il2] * fl;
            xp[1]  = xrow[il]  * fl;
            xp[18] = xrow[ir]  * fr;
            xp[19] = xrow[ir2] * fr;
            float mloc = -INFINITY;
            #pragma unroll
            for (int q = 0; q < 16; ++q) {
                const int s = sbase + q;
                const float x0  = xp[q+2];
                const float am1 = xp[q+1], ap1 = xp[q+3];
                const float am2 = xp[q],   ap2 = xp[q+4];
                const float avg3 = (am1 + x0 + ap1) * (1.f / 3.f);
                const float avg5 = (am2 + am1 + x0 + ap1 + ap2) * 0.2f;
                float mx3 = x0;
                if (s > 0)  mx3 = fmaxf(mx3, am1);
                if (s < 63) mx3 = fmaxf(mx3, ap1);
                float mx5 = mx3;
                if (s > 1)  mx5 = fmaxf(mx5, am2);
                if (s < 62) mx5 = fmaxf(mx5, ap2);
                const float g1 = 1.f / (1.f + __expf(-l1[ch][q]));
                const float g2 = 1.f / (1.f + __expf(-l2[ch][q]));
                const float m = (avg3 + mx3) * g1 + (avg5 + mx5) * g2;
                mloc = fmaxf(mloc, m);
            }
            mloc = fmaxf(mloc, __shfl_xor(mloc, 16, 64));
            mloc = fmaxf(mloc, __shfl_xor(mloc, 32, 64));
            if (sg == 0)
                out[(size_t)blk * CH_ + c] = mloc;
        }
    }
}

extern "C" void kernel_launch(void* const* d_in, const int* in_sizes, int n_in,
                              void* d_out, int out_size, void* d_ws, size_t ws_size,
                              hipStream_t stream) {
    const float* x   = (const float*)d_in[0];
    const float* W1a = (const float*)d_in[1];
    const float* W1b = (const float*)d_in[2];
    const float* W2a = (const float*)d_in[3];
    const float* W2b = (const float*)d_in[4];
    float* out = (float*)d_out;

    if (ws_size >= WS_BYTES) {
        ushort* ws = (ushort*)d_ws;
        ushort* xT = nullptr;
        int xblocks = 0;
        if (ws_size >= WS_FULL_BYTES) {
            xT = ws + WS_ELEMS;
            xblocks = XBLOCKS;
        }
        prep_all<<<dim3(xblocks + NWBLOCKS), dim3(256), 0, stream>>>(
            x, W1a, W1b, W2a, W2b, ws, xT, xblocks);
        tfa_mfma<<<dim3(B_ * PARTS_), dim3(256), 0, stream>>>(x, ws, xT, out);
    } else {
        tfa_fused_fp32<<<dim3(B_ * PARTS_), dim3(256), 0, stream>>>(x, W1a, W1b, W2a, W2b, out);
    }
}